// Round 6
// baseline (248.946 us; speedup 1.0000x reference)
//
#include <hip/hip_runtime.h>
#include <hip/hip_bf16.h>
#include <math.h>

#define NS 4096      // samples
#define NC 512       // clusters
#define ND 64        // feature dim
#define NK 10        // classes
#define NPAIR 2080   // upper-triangle pairs (e<=d) of 64x64
#define KP 2176      // 2080 + 64 (linear) + 1 (const) + 31 zero-pad; 68*32
#define BOFF 2080
#define KOFF 2144
#define KSPLIT 4
#define KT_PER (KP / 32 / KSPLIT)   // 17 k-chunks per split block
#define ZB 1024                     // d2-zeroing blocks
#define QB 2048                     // Q-precompute blocks (2 rows each)

typedef __attribute__((ext_vector_type(8))) short short8;
typedef __attribute__((ext_vector_type(4))) float floatx4;

__device__ inline unsigned short f2b(float x) {
    __hip_bfloat16 h = __float2bfloat16(x);           // RNE
    return __builtin_bit_cast(unsigned short, h);
}
__device__ inline float b2f(unsigned short u) {
    __hip_bfloat16 h = __builtin_bit_cast(__hip_bfloat16, u);
    return __bfloat162float(h);
}

// true v_readlane_b32 (lane is a compile-time literal at every use site)
__device__ inline float rlane(float v, int k) {
    return __builtin_bit_cast(float, __builtin_amdgcn_readlane(__builtin_bit_cast(int, v), k));
}

// async global->LDS, 16B per lane (m97 lever); dst = wave-uniform base + lane*16
__device__ inline void gl16(const void* g, void* l) {
    __builtin_amdgcn_global_load_lds(
        (const __attribute__((address_space(1))) unsigned int*)g,
        (__attribute__((address_space(3))) unsigned int*)l, 16, 0, 0);
}

// analytic (e,d) decode, replaces the edt table (R21: kills table_kernel).
// p < NPAIR: row e = largest e with off(e)<=p, off(e)=e*64-e(e-1)/2; float
// sqrt + integer fixup (float err << 1, single-step guard each way).
__device__ inline uchar2 ed_decode(int p) {
    if (p < NPAIR) {
        const float s = sqrtf((float)(16641 - 8 * p));
        int e = (int)((129.0f - s) * 0.5f);
        int off = e * 64 - (e * (e - 1)) / 2;         // off(e)
        const int offn = off + (64 - e);              // off(e+1)
        if (p >= offn) { off = offn; ++e; }
        else if (p < off) { off -= (65 - e); --e; }
        return make_uchar2((unsigned char)e, (unsigned char)(e + (p - off)));
    } else if (p < KOFF) return make_uchar2((unsigned char)(p - BOFF), 64);
    else if (p == KOFF)  return make_uchar2(64, 64);
    return make_uchar2(65, 65);                       // zero pad
}

// ---------------- prep: 3 roles ---------------------------------------------
//  role A (blk <  NC):            Sigma^-1 (4-wave coop GJ) + beta pack
//  role B (NC <= blk < NC+ZB):    d2 zeroing (+ tile-counter zeroing, blk NC)
//  role C (blk >= NC+ZB):         Q precompute: Qh/Ql[4096][2176] bf16 hi/lo
//     pair products (bit-identical expression to the old in-gemm A-build).
__global__ __launch_bounds__(256, 4) void prep_kernel(
    const float* __restrict__ data, const float* __restrict__ S,
    const float* __restrict__ n, const float* __restrict__ mu,
    const int* __restrict__ clab,
    unsigned short* __restrict__ Qh, unsigned short* __restrict__ Ql,
    unsigned short* __restrict__ Bph, unsigned short* __restrict__ Bpl,
    float* __restrict__ d2, float* __restrict__ labf, int* __restrict__ ctr)
{
    __shared__ float AcolS[ND * (ND + 1)];            // Sinv mirror [64][65]
    __shared__ float cbuf[ND];                        // bvec staging
    __shared__ float rowbuf[2][ND];                   // GJ pivot-row broadcast
    __shared__ float kksS[1];
    __shared__ float zq[2][66];                       // Q-role rows + sentinels

    if (blockIdx.x >= NC + ZB) {                      // ---- role C: Q build --
        const int qb = blockIdx.x - (NC + ZB);        // 0..QB-1
        const int half = threadIdx.x >> 7;            // 2 rows per block
        const int i = threadIdx.x & 127;              // 2 waves per row
        const int row = qb * 2 + half;
        if (i < 64) zq[half][i] = data[(size_t)row * ND + i];
        else if (i == 64) { zq[half][64] = 1.0f; zq[half][65] = 0.0f; }
        __syncthreads();
        const float* __restrict__ zr = zq[half];
        unsigned short* __restrict__ qh = Qh + (size_t)row * KP;
        unsigned short* __restrict__ ql = Ql + (size_t)row * KP;
        #pragma unroll
        for (int t = 0; t < 17; ++t) {                // 17*128 = 2176
            const int p = t * 128 + i;
            const uchar2 ed = ed_decode(p);
            const float v = zr[ed.x] * zr[ed.y];
            const unsigned short h = f2b(v);
            const unsigned short l = f2b(v - b2f(h));
            qh[p] = h;
            ql[p] = l;
        }
        return;
    }

    if (blockIdx.x >= NC) {                           // ---- role B: d2 zero --
        if (blockIdx.x == NC && threadIdx.x < 64) ctr[threadIdx.x] = 0;
        const size_t base = (size_t)(blockIdx.x - NC) * 2048 + threadIdx.x * 8;
        *(float4*)&d2[base]     = make_float4(0.f, 0.f, 0.f, 0.f);
        *(float4*)&d2[base + 4] = make_float4(0.f, 0.f, 0.f, 0.f);
        return;
    }

    // ---- role A: 4-wave cooperative Gauss-Jordan (R16) ----
    const int c = blockIdx.x;
    const int tid = threadIdx.x;
    const int j = tid & 63;                           // column owned by lane
    const int w = tid >> 6;                           // wave -> rows 16w..16w+15
    const int rbase = w * 16;

    const float inv_nc = 1.0f / n[c];
    const float* __restrict__ Sc = S + (size_t)c * ND * ND + j;

    float4 B0, B1, B2, B3;
#define LOADR(u) {                                                   \
    const float x0 = Sc[(rbase + 4*(u) + 0) * ND] * inv_nc;          \
    const float x1 = Sc[(rbase + 4*(u) + 1) * ND] * inv_nc;          \
    const float x2 = Sc[(rbase + 4*(u) + 2) * ND] * inv_nc;          \
    const float x3 = Sc[(rbase + 4*(u) + 3) * ND] * inv_nc;          \
    B##u.x = (rbase + 4*(u) + 0 == j) ? x0 + 1e-6f : x0;             \
    B##u.y = (rbase + 4*(u) + 1 == j) ? x1 + 1e-6f : x1;             \
    B##u.z = (rbase + 4*(u) + 2 == j) ? x2 + 1e-6f : x2;             \
    B##u.w = (rbase + 4*(u) + 3 == j) ? x3 + 1e-6f : x3; }
    LOADR(0) LOADR(1) LOADR(2) LOADR(3)
#undef LOADR

#define UPD4(u, K) {                                                  \
    const float c0 = rlane(B##u.x, K);                                \
    const float c1 = rlane(B##u.y, K);                                \
    const float c2 = rlane(B##u.z, K);                                \
    const float c3 = rlane(B##u.w, K);                                \
    B##u.x = (om && (4*(u)+0 == ((K)&15))) ? rowk : B##u.x * am - c0 * rowk; \
    B##u.y = (om && (4*(u)+1 == ((K)&15))) ? rowk : B##u.y * am - c1 * rowk; \
    B##u.z = (om && (4*(u)+2 == ((K)&15))) ? rowk : B##u.z * am - c2 * rowk; \
    B##u.w = (om && (4*(u)+3 == ((K)&15))) ? rowk : B##u.w * am - c3 * rowk; \
}
#define STEPC(TL, C, K) {                                             \
    if (w == ((K) >> 4)) {                                            \
        const float rp = B##TL.C;         /* M[k][j]: own register */ \
        const float pv = rlane(rp, K);    /* pivot M[k][k] */         \
        const float ip = 1.0f / pv;                                   \
        rowbuf[(K) & 1][j] = (j == (K)) ? ip : rp * ip;               \
    }                                                                 \
    __syncthreads();                                                  \
    const float rowk = rowbuf[(K) & 1][j];                            \
    const float am = (j == (K)) ? 0.0f : 1.0f;                        \
    const bool om = (w == ((K) >> 4));                                \
    UPD4(0, K) UPD4(1, K) UPD4(2, K) UPD4(3, K)                       \
}
#define STEP4(T, TL) STEPC(TL, x, 4*(T)+0) STEPC(TL, y, 4*(T)+1) \
                     STEPC(TL, z, 4*(T)+2) STEPC(TL, w, 4*(T)+3)
#define FOR16P(M) M(0,0) M(1,1) M(2,2) M(3,3) M(4,0) M(5,1) M(6,2) M(7,3) \
                  M(8,0) M(9,1) M(10,2) M(11,3) M(12,0) M(13,1) M(14,2) M(15,3)
    FOR16P(STEP4)
#undef FOR16P
#undef STEP4
#undef STEPC
#undef UPD4

    // mirror Sinv into LDS for the pack gather (all 4 waves, disjoint rows)
#define MIR(u) *(float4*)&AcolS[j * (ND + 1) + rbase + 4*(u)] = B##u;
    MIR(0) MIR(1) MIR(2) MIR(3)
#undef MIR
    __syncthreads();                                  // AcolS complete

    if (w == 0) {                                     // y = Sinv*mu, kk, labels
        const float* __restrict__ muc = mu + (size_t)c * ND;
        float y = 0.f;
        #pragma unroll
        for (int t = 0; t < 16; ++t) {
            const float4 v = *(const float4*)&AcolS[j * (ND + 1) + 4 * t];
            y += v.x * muc[4*t]     + v.y * muc[4*t + 1]
               + v.z * muc[4*t + 2] + v.w * muc[4*t + 3];
        }
        cbuf[j] = -2.0f * y;                          // bvec values
        float kk = muc[j] * y;
        #pragma unroll
        for (int off = 32; off > 0; off >>= 1) kk += __shfl_down(kk, off);
        if (j == 0) {
            kksS[0] = kk;
            int lab = 0;
            for (int q = 0; q < NK; ++q) if (clab[c * NK + q] != 0) lab = q;
            labf[c] = (float)lab;
        }
    }
    __syncthreads();
    const float kks = kksS[0];

    unsigned short* __restrict__ ph = Bph + (size_t)c * KP;
    unsigned short* __restrict__ pl = Bpl + (size_t)c * KP;
    #pragma unroll
    for (int i = 0; i < 9; ++i) {                     // 34 iters split 4 ways
        const int t = w + 4 * i;
        if (t < KP / 64) {
            const int p = t * 64 + j;
            float val;
            if (p < NPAIR) {
                const uchar2 ed = ed_decode(p);
                val = (ed.x == ed.y) ? AcolS[ed.x * (ND + 1) + ed.x]
                    : (AcolS[ed.y * (ND + 1) + ed.x] + AcolS[ed.x * (ND + 1) + ed.y]);
            } else if (p < KOFF) val = cbuf[p - BOFF];
            else if (p == KOFF)  val = kks;
            else                 val = 0.f;
            const unsigned short h = f2b(val);
            const unsigned short l = f2b(val - b2f(h));
            ph[p] = h;
            pl[p] = l;
        }
    }
}

// ---------------- d2 = Q·Beta^T (R4 structure) + FUSED SCORE EPILOGUE -------
// R21: R0's budget audit shows ~60us of the 150 total is inter-launch
// overhead (4 sequential launches, ~15us each; score/table themselves are
// ~3us by arithmetic). gemm K-loop kept byte-identical to R4 (best measured,
// 54us). New: per-m-tile completion counters -- each m-tile has 8 contributing
// blocks (2 n-tiles x 4 k-splits); the 8th finisher acquires and runs the
// score for its 64 samples with code identical to the old score_kernel
// (same loop order, same shuffle reduce, same tie-breaks -> same bits).
__global__ __launch_bounds__(256, 2) void gemm_kernel(
    const unsigned short* __restrict__ Qh, const unsigned short* __restrict__ Ql,
    const unsigned short* __restrict__ Bph, const unsigned short* __restrict__ Bpl,
    float* __restrict__ d2, const float* __restrict__ labf,
    int* __restrict__ ctr, float* __restrict__ out)
{
    __shared__ unsigned short AhS[2][64 * 32], AlS[2][64 * 32];   // 16KB
    __shared__ unsigned short BhS[2][256 * 32], BlS[2][256 * 32]; // 64KB
    // NOTE: exactly 80KB -> 2 blocks/CU; epilogue flag reuses dead AhS space.

    const int tid  = threadIdx.x;
    const int lane = tid & 63, w = tid >> 6;
    const int quad = lane >> 4, rlo = lane & 15;

    // T1 XCD remap: lid%8 selects (y,z) -> one B-slice per XCD (L2-resident)
    const int lid = blockIdx.x + 64 * blockIdx.y + 128 * blockIdx.z;
    const int nyz = lid & 7;
    const int m0 = (lid >> 3) * 64;               // sample tile
    const int n0 = (nyz & 1) * 256;               // cluster tile
    const int koff0 = (nyz >> 1) * KT_PER * 32;   // K-slice start

    // staging: thread -> LDS row tid>>2, slot tid&3 (dst linear = tid*16B);
    // source segment pre-swizzled so LDS[row][slot] = global seg slot^((row>>2)&3)
    const int srow = tid >> 2;
    const int sswz = (tid & 3) ^ ((srow >> 2) & 3);
    const unsigned short* aGh = Qh + (size_t)(m0 + srow) * KP + koff0 + sswz * 8;
    const unsigned short* aGl = Ql + (size_t)(m0 + srow) * KP + koff0 + sswz * 8;
    const unsigned short* bGh[4];
    const unsigned short* bGl[4];
    #pragma unroll
    for (int rd = 0; rd < 4; ++rd) {
        const size_t off = (size_t)(n0 + rd * 64 + srow) * KP + koff0 + sswz * 8;
        bGh[rd] = Bph + off;
        bGl[rd] = Bpl + off;
    }
    const int swz8 = (quad ^ ((rlo >> 2) & 3)) * 8;   // read-side slot

    floatx4 acc[4][4] = {};

#define STAGE(b, t) {                                                 \
        const int _ko = (t) * 32;                                     \
        gl16(aGh + _ko, &AhS[b][tid * 8]);                            \
        gl16(aGl + _ko, &AlS[b][tid * 8]);                            \
        _Pragma("unroll")                                             \
        for (int rd = 0; rd < 4; ++rd) {                              \
            gl16(bGh[rd] + _ko, &BhS[b][(rd * 256 + tid) * 8]);       \
            gl16(bGl[rd] + _ko, &BlS[b][(rd * 256 + tid) * 8]);       \
        } }

    // prologue: tiles 0 and 1 in flight; wait only for tile 0
    STAGE(0, 0)
    STAGE(1, 1)
    asm volatile("s_waitcnt vmcnt(10)" ::: "memory");
    __builtin_amdgcn_s_barrier();

    for (int kt = 0; kt < KT_PER; ++kt) {
        const int cur = kt & 1;

        short8 ah[4], al[4], bh[4], bl[4];
        #pragma unroll
        for (int i = 0; i < 4; ++i) {
            ah[i] = *(const short8*)&AhS[cur][(i * 16 + rlo) * 32 + swz8];
            al[i] = *(const short8*)&AlS[cur][(i * 16 + rlo) * 32 + swz8];
        }
        #pragma unroll
        for (int j2 = 0; j2 < 4; ++j2) {
            const int r = w * 64 + j2 * 16 + rlo;
            bh[j2] = *(const short8*)&BhS[cur][r * 32 + swz8];
            bl[j2] = *(const short8*)&BlS[cur][r * 32 + swz8];
        }
        asm volatile("s_waitcnt lgkmcnt(0)" ::: "memory");
        __builtin_amdgcn_sched_barrier(0);
        __builtin_amdgcn_s_barrier();     // all waves hold frags; cur reusable

        if (kt < KT_PER - 2) STAGE(cur, kt + 2)

        __builtin_amdgcn_s_setprio(1);
        #pragma unroll
        for (int i = 0; i < 4; ++i)
            #pragma unroll
            for (int j2 = 0; j2 < 4; ++j2) {
                acc[i][j2] = __builtin_amdgcn_mfma_f32_16x16x32_bf16(al[i], bh[j2], acc[i][j2], 0, 0, 0);
                acc[i][j2] = __builtin_amdgcn_mfma_f32_16x16x32_bf16(ah[i], bl[j2], acc[i][j2], 0, 0, 0);
                acc[i][j2] = __builtin_amdgcn_mfma_f32_16x16x32_bf16(ah[i], bh[j2], acc[i][j2], 0, 0, 0);
            }
        __builtin_amdgcn_s_setprio(0);

        if (kt < KT_PER - 2) {
            asm volatile("s_waitcnt vmcnt(10)" ::: "memory");  // kt+1 landed
        } else {
            asm volatile("s_waitcnt vmcnt(0)" ::: "memory");   // tail drain
        }
        __builtin_amdgcn_s_barrier();
    }
#undef STAGE

    // C layout (verified m89): col = lane&15, row = (lane>>4)*4 + reg
    #pragma unroll
    for (int i = 0; i < 4; ++i)
        #pragma unroll
        for (int j2 = 0; j2 < 4; ++j2) {
            const int m = m0 + i * 16 + quad * 4;
            const int nn = n0 + w * 64 + j2 * 16 + rlo;
            #pragma unroll
            for (int r = 0; r < 4; ++r)
                atomicAdd(&d2[(size_t)(m + r) * NC + nn], acc[i][j2][r]);
        }

    // ---- fused score epilogue: 8th finisher per m-tile scores 64 samples ---
    __threadfence();                                  // release: atomics done
    __syncthreads();
    volatile int* flag = (volatile int*)&AhS[0][0];   // dead staging space
    if (tid == 0) *flag = atomicAdd(&ctr[m0 >> 6], 1);
    __syncthreads();
    if (*flag != KSPLIT * 2 - 1) return;              // not last of 8
    __threadfence();                                  // acquire: L1 invalidate

    const int l = lane;
    for (int it = 0; it < 16; ++it) {                 // 4 waves x 16 samples
        const int s = m0 + w * 16 + it;

        float numer[NK];
        #pragma unroll
        for (int q = 0; q < NK; ++q) numer[q] = 0.f;
        float denom = 0.f, gmax = -1.f;
        int gidx = 0;

        #pragma unroll
        for (int i = 0; i < NC / 256; ++i) {     // float4/lane, index-ascending
            const int c0 = i * 256 + l * 4;
            const float4 v = *(const float4*)&d2[(size_t)s * NC + c0];
            #pragma unroll
            for (int r = 0; r < 4; ++r) {
                const int c = c0 + r;
                const float G = __expf(-0.5f * ((const float*)&v)[r]);
                denom += G;
                const int lab = (int)labf[c];
                #pragma unroll
                for (int q = 0; q < NK; ++q) numer[q] += (q == lab) ? G : 0.f;
                if (G > gmax) { gmax = G; gidx = c; }  // strict > keeps first
            }
        }

        #pragma unroll
        for (int off = 32; off > 0; off >>= 1) {
            const float og = __shfl_down(gmax, off);
            const int   oi = __shfl_down(gidx, off);
            if (og > gmax || (og == gmax && oi < gidx)) { gmax = og; gidx = oi; }
            denom += __shfl_down(denom, off);
            #pragma unroll
            for (int q = 0; q < NK; ++q) numer[q] += __shfl_down(numer[q], off);
        }

        if (l == 0) {
            const float inv = 1.0f / (denom + 1e-12f);
            float best = -1.f; int pk = 0;
            #pragma unroll
            for (int q = 0; q < NK; ++q) {
                const float sc = numer[q] * inv;
                out[(size_t)s * NK + q] = sc;
                if (sc > best) { best = sc; pk = q; }
            }
            out[(size_t)NS * NK + s]      = (float)pk;    // pred
            out[(size_t)NS * NK + NS + s] = (float)gidx;  // clusters
        }
    }
}

extern "C" void kernel_launch(void* const* d_in, const int* in_sizes, int n_in,
                              void* d_out, int out_size, void* d_ws, size_t ws_size,
                              hipStream_t stream)
{
    const float* data = (const float*)d_in[0];
    const float* n    = (const float*)d_in[2];
    const float* mu   = (const float*)d_in[3];
    const float* S    = (const float*)d_in[4];
    const int*   clab = (const int*)d_in[5];

    char* w = (char*)d_ws;
    unsigned short* Qh  = (unsigned short*)(w);                 // 17,825,792 B
    unsigned short* Ql  = (unsigned short*)(w + 17825792);      // 17,825,792 B
    unsigned short* Bph = (unsigned short*)(w + 35651584);      //  2,228,224 B
    unsigned short* Bpl = (unsigned short*)(w + 37879808);      //  2,228,224 B
    float* d2   = (float*)(w + 40108032);                       //  8,388,608 B
    float* labf = (float*)(w + 48496640);                       //      2,048 B
    int*   ctr  = (int*)(w + 48498688);                         //        256 B

    hipLaunchKernelGGL(prep_kernel,  dim3(NC + ZB + QB), dim3(256), 0, stream,
                       data, S, n, mu, clab, Qh, Ql, Bph, Bpl, d2, labf, ctr);
    hipLaunchKernelGGL(gemm_kernel,  dim3(NS / 64, NC / 256, KSPLIT), dim3(256), 0, stream,
                       Qh, Ql, Bph, Bpl, d2, labf, ctr, (float*)d_out);
}

// Round 7
// 149.152 us; speedup vs baseline: 1.6691x; 1.6691x over previous
//
#include <hip/hip_runtime.h>
#include <hip/hip_bf16.h>
#include <math.h>

#define NS 4096      // samples
#define NC 512       // clusters
#define ND 64        // feature dim
#define NK 10        // classes
#define NPAIR 2080   // upper-triangle pairs (e<=d) of 64x64
#define KP 2176      // 2080 + 64 (linear) + 1 (const) + 31 zero-pad; 68*32
#define BOFF 2080
#define KOFF 2144
#define KSPLIT 4
#define KT_PER (KP / 32 / KSPLIT)   // 17 k-chunks per split block
#define ZB 1024                     // d2-zeroing blocks
#define QB 2048                     // Q-precompute blocks (2 rows each)

typedef __attribute__((ext_vector_type(8))) short short8;
typedef __attribute__((ext_vector_type(4))) float floatx4;

__device__ inline unsigned short f2b(float x) {
    __hip_bfloat16 h = __float2bfloat16(x);           // RNE
    return __builtin_bit_cast(unsigned short, h);
}
__device__ inline float b2f(unsigned short u) {
    __hip_bfloat16 h = __builtin_bit_cast(__hip_bfloat16, u);
    return __bfloat162float(h);
}

// true v_readlane_b32 (lane is a compile-time literal at every use site)
__device__ inline float rlane(float v, int k) {
    return __builtin_bit_cast(float, __builtin_amdgcn_readlane(__builtin_bit_cast(int, v), k));
}

// async global->LDS, 16B per lane (m97 lever); dst = wave-uniform base + lane*16
__device__ inline void gl16(const void* g, void* l) {
    __builtin_amdgcn_global_load_lds(
        (const __attribute__((address_space(1))) unsigned int*)g,
        (__attribute__((address_space(3))) unsigned int*)l, 16, 0, 0);
}

// analytic (e,d) decode (replaces table_kernel; bit-exact, HW-verified in R6:
// absmax 0.0 end-to-end). p < NPAIR: e = largest e with off(e)<=p where
// off(e)=e*64-e(e-1)/2; float sqrt + single-step integer fixup each way.
__device__ inline uchar2 ed_decode(int p) {
    if (p < NPAIR) {
        const float s = sqrtf((float)(16641 - 8 * p));
        int e = (int)((129.0f - s) * 0.5f);
        int off = e * 64 - (e * (e - 1)) / 2;         // off(e)
        const int offn = off + (64 - e);              // off(e+1)
        if (p >= offn) { off = offn; ++e; }
        else if (p < off) { off -= (65 - e); --e; }
        return make_uchar2((unsigned char)e, (unsigned char)(e + (p - off)));
    } else if (p < KOFF) return make_uchar2((unsigned char)(p - BOFF), 64);
    else if (p == KOFF)  return make_uchar2(64, 64);
    return make_uchar2(65, 65);                       // zero pad
}

// ---------------- prep: 3 roles ---------------------------------------------
//  role A (blk <  NC):            Sigma^-1 (4-wave coop GJ) + beta pack
//  role B (NC <= blk < NC+ZB):    d2 zeroing
//  role C (blk >= NC+ZB):         Q precompute: Qh/Ql[4096][2176] bf16 hi/lo
//     pair products (bit-identical expression to the old in-gemm A-build).
__global__ __launch_bounds__(256, 4) void prep_kernel(
    const float* __restrict__ data, const float* __restrict__ S,
    const float* __restrict__ n, const float* __restrict__ mu,
    const int* __restrict__ clab,
    unsigned short* __restrict__ Qh, unsigned short* __restrict__ Ql,
    unsigned short* __restrict__ Bph, unsigned short* __restrict__ Bpl,
    float* __restrict__ d2, float* __restrict__ labf)
{
    __shared__ float AcolS[ND * (ND + 1)];            // Sinv mirror [64][65]
    __shared__ float cbuf[ND];                        // bvec staging
    __shared__ float rowbuf[2][ND];                   // GJ pivot-row broadcast
    __shared__ float kksS[1];
    __shared__ float zq[2][66];                       // Q-role rows + sentinels

    if (blockIdx.x >= NC + ZB) {                      // ---- role C: Q build --
        const int qb = blockIdx.x - (NC + ZB);        // 0..QB-1
        const int half = threadIdx.x >> 7;            // 2 rows per block
        const int i = threadIdx.x & 127;              // 2 waves per row
        const int row = qb * 2 + half;
        if (i < 64) zq[half][i] = data[(size_t)row * ND + i];
        else if (i == 64) { zq[half][64] = 1.0f; zq[half][65] = 0.0f; }
        __syncthreads();
        const float* __restrict__ zr = zq[half];
        unsigned short* __restrict__ qh = Qh + (size_t)row * KP;
        unsigned short* __restrict__ ql = Ql + (size_t)row * KP;
        #pragma unroll
        for (int t = 0; t < 17; ++t) {                // 17*128 = 2176
            const int p = t * 128 + i;
            const uchar2 ed = ed_decode(p);
            const float v = zr[ed.x] * zr[ed.y];
            const unsigned short h = f2b(v);
            const unsigned short l = f2b(v - b2f(h));
            qh[p] = h;
            ql[p] = l;
        }
        return;
    }

    if (blockIdx.x >= NC) {                           // ---- role B: d2 zero --
        const size_t base = (size_t)(blockIdx.x - NC) * 2048 + threadIdx.x * 8;
        *(float4*)&d2[base]     = make_float4(0.f, 0.f, 0.f, 0.f);
        *(float4*)&d2[base + 4] = make_float4(0.f, 0.f, 0.f, 0.f);
        return;
    }

    // ---- role A: 4-wave cooperative Gauss-Jordan (R16) ----
    const int c = blockIdx.x;
    const int tid = threadIdx.x;
    const int j = tid & 63;                           // column owned by lane
    const int w = tid >> 6;                           // wave -> rows 16w..16w+15
    const int rbase = w * 16;

    const float inv_nc = 1.0f / n[c];
    const float* __restrict__ Sc = S + (size_t)c * ND * ND + j;

    float4 B0, B1, B2, B3;
#define LOADR(u) {                                                   \
    const float x0 = Sc[(rbase + 4*(u) + 0) * ND] * inv_nc;          \
    const float x1 = Sc[(rbase + 4*(u) + 1) * ND] * inv_nc;          \
    const float x2 = Sc[(rbase + 4*(u) + 2) * ND] * inv_nc;          \
    const float x3 = Sc[(rbase + 4*(u) + 3) * ND] * inv_nc;          \
    B##u.x = (rbase + 4*(u) + 0 == j) ? x0 + 1e-6f : x0;             \
    B##u.y = (rbase + 4*(u) + 1 == j) ? x1 + 1e-6f : x1;             \
    B##u.z = (rbase + 4*(u) + 2 == j) ? x2 + 1e-6f : x2;             \
    B##u.w = (rbase + 4*(u) + 3 == j) ? x3 + 1e-6f : x3; }
    LOADR(0) LOADR(1) LOADR(2) LOADR(3)
#undef LOADR

#define UPD4(u, K) {                                                  \
    const float c0 = rlane(B##u.x, K);                                \
    const float c1 = rlane(B##u.y, K);                                \
    const float c2 = rlane(B##u.z, K);                                \
    const float c3 = rlane(B##u.w, K);                                \
    B##u.x = (om && (4*(u)+0 == ((K)&15))) ? rowk : B##u.x * am - c0 * rowk; \
    B##u.y = (om && (4*(u)+1 == ((K)&15))) ? rowk : B##u.y * am - c1 * rowk; \
    B##u.z = (om && (4*(u)+2 == ((K)&15))) ? rowk : B##u.z * am - c2 * rowk; \
    B##u.w = (om && (4*(u)+3 == ((K)&15))) ? rowk : B##u.w * am - c3 * rowk; \
}
#define STEPC(TL, C, K) {                                             \
    if (w == ((K) >> 4)) {                                            \
        const float rp = B##TL.C;         /* M[k][j]: own register */ \
        const float pv = rlane(rp, K);    /* pivot M[k][k] */         \
        const float ip = 1.0f / pv;                                   \
        rowbuf[(K) & 1][j] = (j == (K)) ? ip : rp * ip;               \
    }                                                                 \
    __syncthreads();                                                  \
    const float rowk = rowbuf[(K) & 1][j];                            \
    const float am = (j == (K)) ? 0.0f : 1.0f;                        \
    const bool om = (w == ((K) >> 4));                                \
    UPD4(0, K) UPD4(1, K) UPD4(2, K) UPD4(3, K)                       \
}
#define STEP4(T, TL) STEPC(TL, x, 4*(T)+0) STEPC(TL, y, 4*(T)+1) \
                     STEPC(TL, z, 4*(T)+2) STEPC(TL, w, 4*(T)+3)
#define FOR16P(M) M(0,0) M(1,1) M(2,2) M(3,3) M(4,0) M(5,1) M(6,2) M(7,3) \
                  M(8,0) M(9,1) M(10,2) M(11,3) M(12,0) M(13,1) M(14,2) M(15,3)
    FOR16P(STEP4)
#undef FOR16P
#undef STEP4
#undef STEPC
#undef UPD4

    // mirror Sinv into LDS for the pack gather (all 4 waves, disjoint rows)
#define MIR(u) *(float4*)&AcolS[j * (ND + 1) + rbase + 4*(u)] = B##u;
    MIR(0) MIR(1) MIR(2) MIR(3)
#undef MIR
    __syncthreads();                                  // AcolS complete

    if (w == 0) {                                     // y = Sinv*mu, kk, labels
        const float* __restrict__ muc = mu + (size_t)c * ND;
        float y = 0.f;
        #pragma unroll
        for (int t = 0; t < 16; ++t) {
            const float4 v = *(const float4*)&AcolS[j * (ND + 1) + 4 * t];
            y += v.x * muc[4*t]     + v.y * muc[4*t + 1]
               + v.z * muc[4*t + 2] + v.w * muc[4*t + 3];
        }
        cbuf[j] = -2.0f * y;                          // bvec values
        float kk = muc[j] * y;
        #pragma unroll
        for (int off = 32; off > 0; off >>= 1) kk += __shfl_down(kk, off);
        if (j == 0) {
            kksS[0] = kk;
            int lab = 0;
            for (int q = 0; q < NK; ++q) if (clab[c * NK + q] != 0) lab = q;
            labf[c] = (float)lab;
        }
    }
    __syncthreads();
    const float kks = kksS[0];

    unsigned short* __restrict__ ph = Bph + (size_t)c * KP;
    unsigned short* __restrict__ pl = Bpl + (size_t)c * KP;
    #pragma unroll
    for (int i = 0; i < 9; ++i) {                     // 34 iters split 4 ways
        const int t = w + 4 * i;
        if (t < KP / 64) {
            const int p = t * 64 + j;
            float val;
            if (p < NPAIR) {
                const uchar2 ed = ed_decode(p);
                val = (ed.x == ed.y) ? AcolS[ed.x * (ND + 1) + ed.x]
                    : (AcolS[ed.y * (ND + 1) + ed.x] + AcolS[ed.x * (ND + 1) + ed.y]);
            } else if (p < KOFF) val = cbuf[p - BOFF];
            else if (p == KOFF)  val = kks;
            else                 val = 0.f;
            const unsigned short h = f2b(val);
            const unsigned short l = f2b(val - b2f(h));
            ph[p] = h;
            pl[p] = l;
        }
    }
}

// ---------------- d2 = Q·Beta^T, T3+T4 pipeline + T1 XCD remap --------------
// R22: byte-identical to R4 (best measured: 54us). R6's fused-score variant
// (device-scope fences + completion counters) poisoned this kernel 3.2x --
// reverted; score stays a separate launch.
__global__ __launch_bounds__(256, 2) void gemm_kernel(
    const unsigned short* __restrict__ Qh, const unsigned short* __restrict__ Ql,
    const unsigned short* __restrict__ Bph, const unsigned short* __restrict__ Bpl,
    float* __restrict__ d2)
{
    __shared__ unsigned short AhS[2][64 * 32], AlS[2][64 * 32];   // 16KB
    __shared__ unsigned short BhS[2][256 * 32], BlS[2][256 * 32]; // 64KB

    const int tid  = threadIdx.x;
    const int lane = tid & 63, w = tid >> 6;
    const int quad = lane >> 4, rlo = lane & 15;

    // T1 XCD remap: lid%8 selects (y,z) -> one B-slice per XCD (L2-resident)
    const int lid = blockIdx.x + 64 * blockIdx.y + 128 * blockIdx.z;
    const int nyz = lid & 7;
    const int m0 = (lid >> 3) * 64;               // sample tile
    const int n0 = (nyz & 1) * 256;               // cluster tile
    const int koff0 = (nyz >> 1) * KT_PER * 32;   // K-slice start

    // staging: thread -> LDS row tid>>2, slot tid&3 (dst linear = tid*16B);
    // source segment pre-swizzled so LDS[row][slot] = global seg slot^((row>>2)&3)
    const int srow = tid >> 2;
    const int sswz = (tid & 3) ^ ((srow >> 2) & 3);
    const unsigned short* aGh = Qh + (size_t)(m0 + srow) * KP + koff0 + sswz * 8;
    const unsigned short* aGl = Ql + (size_t)(m0 + srow) * KP + koff0 + sswz * 8;
    const unsigned short* bGh[4];
    const unsigned short* bGl[4];
    #pragma unroll
    for (int rd = 0; rd < 4; ++rd) {
        const size_t off = (size_t)(n0 + rd * 64 + srow) * KP + koff0 + sswz * 8;
        bGh[rd] = Bph + off;
        bGl[rd] = Bpl + off;
    }
    const int swz8 = (quad ^ ((rlo >> 2) & 3)) * 8;   // read-side slot

    floatx4 acc[4][4] = {};

#define STAGE(b, t) {                                                 \
        const int _ko = (t) * 32;                                     \
        gl16(aGh + _ko, &AhS[b][tid * 8]);                            \
        gl16(aGl + _ko, &AlS[b][tid * 8]);                            \
        _Pragma("unroll")                                             \
        for (int rd = 0; rd < 4; ++rd) {                              \
            gl16(bGh[rd] + _ko, &BhS[b][(rd * 256 + tid) * 8]);       \
            gl16(bGl[rd] + _ko, &BlS[b][(rd * 256 + tid) * 8]);       \
        } }

    // prologue: tiles 0 and 1 in flight; wait only for tile 0
    STAGE(0, 0)
    STAGE(1, 1)
    asm volatile("s_waitcnt vmcnt(10)" ::: "memory");
    __builtin_amdgcn_s_barrier();

    for (int kt = 0; kt < KT_PER; ++kt) {
        const int cur = kt & 1;

        short8 ah[4], al[4], bh[4], bl[4];
        #pragma unroll
        for (int i = 0; i < 4; ++i) {
            ah[i] = *(const short8*)&AhS[cur][(i * 16 + rlo) * 32 + swz8];
            al[i] = *(const short8*)&AlS[cur][(i * 16 + rlo) * 32 + swz8];
        }
        #pragma unroll
        for (int j2 = 0; j2 < 4; ++j2) {
            const int r = w * 64 + j2 * 16 + rlo;
            bh[j2] = *(const short8*)&BhS[cur][r * 32 + swz8];
            bl[j2] = *(const short8*)&BlS[cur][r * 32 + swz8];
        }
        asm volatile("s_waitcnt lgkmcnt(0)" ::: "memory");
        __builtin_amdgcn_sched_barrier(0);
        __builtin_amdgcn_s_barrier();     // all waves hold frags; cur reusable

        if (kt < KT_PER - 2) STAGE(cur, kt + 2)

        __builtin_amdgcn_s_setprio(1);
        #pragma unroll
        for (int i = 0; i < 4; ++i)
            #pragma unroll
            for (int j2 = 0; j2 < 4; ++j2) {
                acc[i][j2] = __builtin_amdgcn_mfma_f32_16x16x32_bf16(al[i], bh[j2], acc[i][j2], 0, 0, 0);
                acc[i][j2] = __builtin_amdgcn_mfma_f32_16x16x32_bf16(ah[i], bl[j2], acc[i][j2], 0, 0, 0);
                acc[i][j2] = __builtin_amdgcn_mfma_f32_16x16x32_bf16(ah[i], bh[j2], acc[i][j2], 0, 0, 0);
            }
        __builtin_amdgcn_s_setprio(0);

        if (kt < KT_PER - 2) {
            asm volatile("s_waitcnt vmcnt(10)" ::: "memory");  // kt+1 landed
        } else {
            asm volatile("s_waitcnt vmcnt(0)" ::: "memory");   // tail drain
        }
        __builtin_amdgcn_s_barrier();
    }
#undef STAGE

    // C layout (verified m89): col = lane&15, row = (lane>>4)*4 + reg
    #pragma unroll
    for (int i = 0; i < 4; ++i)
        #pragma unroll
        for (int j2 = 0; j2 < 4; ++j2) {
            const int m = m0 + i * 16 + quad * 4;
            const int nn = n0 + w * 64 + j2 * 16 + rlo;
            #pragma unroll
            for (int r = 0; r < 4; ++r)
                atomicAdd(&d2[(size_t)(m + r) * NC + nn], acc[i][j2][r]);
        }
}

// ---------------- scores / argmaxes: 4 waves/block, one sample per wave -----
__global__ __launch_bounds__(256) void score_kernel(
    const float* __restrict__ d2, const float* __restrict__ labf,
    float* __restrict__ out)
{
    const int s = blockIdx.x * 4 + (threadIdx.x >> 6);
    const int l = threadIdx.x & 63;

    float numer[NK];
    #pragma unroll
    for (int q = 0; q < NK; ++q) numer[q] = 0.f;
    float denom = 0.f, gmax = -1.f;
    int gidx = 0;

    #pragma unroll
    for (int i = 0; i < NC / 256; ++i) {         // float4 per lane, index-ascending
        const int c0 = i * 256 + l * 4;
        const float4 v = *(const float4*)&d2[(size_t)s * NC + c0];
        #pragma unroll
        for (int r = 0; r < 4; ++r) {
            const int c = c0 + r;
            const float G = __expf(-0.5f * ((const float*)&v)[r]);
            denom += G;
            const int lab = (int)labf[c];
            #pragma unroll
            for (int q = 0; q < NK; ++q) numer[q] += (q == lab) ? G : 0.f;
            if (G > gmax) { gmax = G; gidx = c; }   // strict > keeps first index
        }
    }

    #pragma unroll
    for (int off = 32; off > 0; off >>= 1) {
        const float og = __shfl_down(gmax, off);
        const int   oi = __shfl_down(gidx, off);
        if (og > gmax || (og == gmax && oi < gidx)) { gmax = og; gidx = oi; }
        denom += __shfl_down(denom, off);
        #pragma unroll
        for (int q = 0; q < NK; ++q) numer[q] += __shfl_down(numer[q], off);
    }

    if (l == 0) {
        const float inv = 1.0f / (denom + 1e-12f);
        float best = -1.f; int pk = 0;
        #pragma unroll
        for (int q = 0; q < NK; ++q) {
            const float sc = numer[q] * inv;
            out[(size_t)s * NK + q] = sc;
            if (sc > best) { best = sc; pk = q; }
        }
        out[(size_t)NS * NK + s]      = (float)pk;    // pred
        out[(size_t)NS * NK + NS + s] = (float)gidx;  // clusters
    }
}

extern "C" void kernel_launch(void* const* d_in, const int* in_sizes, int n_in,
                              void* d_out, int out_size, void* d_ws, size_t ws_size,
                              hipStream_t stream)
{
    const float* data = (const float*)d_in[0];
    const float* n    = (const float*)d_in[2];
    const float* mu   = (const float*)d_in[3];
    const float* S    = (const float*)d_in[4];
    const int*   clab = (const int*)d_in[5];

    char* w = (char*)d_ws;
    unsigned short* Qh  = (unsigned short*)(w);                 // 17,825,792 B
    unsigned short* Ql  = (unsigned short*)(w + 17825792);      // 17,825,792 B
    unsigned short* Bph = (unsigned short*)(w + 35651584);      //  2,228,224 B
    unsigned short* Bpl = (unsigned short*)(w + 37879808);      //  2,228,224 B
    float* d2   = (float*)(w + 40108032);                       //  8,388,608 B
    float* labf = (float*)(w + 48496640);                       //      2,048 B

    hipLaunchKernelGGL(prep_kernel,  dim3(NC + ZB + QB), dim3(256), 0, stream,
                       data, S, n, mu, clab, Qh, Ql, Bph, Bpl, d2, labf);
    hipLaunchKernelGGL(gemm_kernel,  dim3(NS / 64, NC / 256, KSPLIT), dim3(256), 0, stream,
                       Qh, Ql, Bph, Bpl, d2);
    hipLaunchKernelGGL(score_kernel, dim3(NS / 4), dim3(256), 0, stream,
                       d2, labf, (float*)d_out);
}